// Round 6
// baseline (1277.695 us; speedup 1.0000x reference)
//
#include <hip/hip_runtime.h>
#include <hip/hip_bf16.h>
#include <stdint.h>

#define NB 16
#define NPTS 4096
#define NS 1024
#define NK 32
#define NT_COLS (NB*NS*NK)   // 524288 columns (b*NS+s)*NK + k

typedef __hip_bfloat16 bf16;

__global__ void k_zero(float* __restrict__ p) { p[threadIdx.x] = 0.f; }

// DPP-shifted fmax: returns fmax(x, dpp_mov(x)). Disabled/OOB lanes keep old=x
// (identity). Verified working on gfx950 in round 5 (passed).
template<int CTRL, int RM, int BM>
__device__ __forceinline__ float fmax_dpp(float x) {
  int o = __builtin_amdgcn_update_dpp(__float_as_int(x), __float_as_int(x),
                                      CTRL, RM, BM, false);
  return fmaxf(x, __int_as_float(o));
}

__device__ __forceinline__ float4 sel4(float4 A, float4 B) {
  // prefer B only on strict greater -> lower-index operand wins ties
  return (B.x > A.x) ? B : A;
}

// ---------------- FPS: one block/batch, 256 thr, coord-tracking argmax ------
// Exact np replication: per-point (x-c)^2 elementwise + sequential 3-term sum
// (no FMA); argmax tie-break = first occurrence at every level:
//   in-lane strict >, in-wave lowest lane via ctz(ballot), cross-wave strict >
//   in wave order (waves own ascending contiguous index ranges).
__global__ __launch_bounds__(256) void k_fps(const float* __restrict__ xyz,
                                             float* __restrict__ newxyz,
                                             float* __restrict__ out0) {
  __shared__ float xs[NPTS], ys[NPTS], zs[NPTS];
  __shared__ float4 pairbuf[2][4];          // double-buffered per-wave winner
  __shared__ float selx[NS], sely[NS], selz[NS];
  const int b = blockIdx.x;
  const int t = threadIdx.x;
  const float* p = xyz + (size_t)b * 3 * NPTS;
  for (int i = t; i < NPTS; i += 256) {
    xs[i] = p[i];
    ys[i] = p[NPTS + i];
    zs[i] = p[2*NPTS + i];
  }
  __syncthreads();
  float px[16], py[16], pz[16], dist[16];
  const int p0 = t * 16;                    // lane-contiguous point ownership
  #pragma unroll
  for (int j = 0; j < 16; ++j) {
    px[j]=xs[p0+j]; py[j]=ys[p0+j]; pz[j]=zs[p0+j]; dist[j]=1e10f;
  }
  const int lane = t & 63, wv = t >> 6;
  float cx = xs[0], cy = ys[0], cz = zs[0]; // first centroid = point 0
  if (t == 0) { selx[0] = cx; sely[0] = cy; selz[0] = cz; }
  for (int i = 1; i < NS; ++i) {
    float bv = -1.0f, bx = 0.f, by = 0.f, bz = 0.f;
    #pragma unroll
    for (int j = 0; j < 16; ++j) {
      float dx = __fsub_rn(px[j], cx);
      float dy = __fsub_rn(py[j], cy);
      float dz = __fsub_rn(pz[j], cz);
      float d  = __fadd_rn(__fadd_rn(__fmul_rn(dx,dx), __fmul_rn(dy,dy)), __fmul_rn(dz,dz));
      float nd = fminf(dist[j], d);
      dist[j] = nd;
      if (nd > bv) { bv = nd; bx = px[j]; by = py[j]; bz = pz[j]; }
    }
    // wave64 max via DPP chain (converges to lane 63)
    float x = bv;
    x = fmax_dpp<0x111,0xF,0xF>(x);   // row_shr:1
    x = fmax_dpp<0x112,0xF,0xF>(x);   // row_shr:2
    x = fmax_dpp<0x114,0xF,0xF>(x);   // row_shr:4
    x = fmax_dpp<0x118,0xF,0xF>(x);   // row_shr:8
    x = fmax_dpp<0x142,0xA,0xF>(x);   // row_bcast:15 -> rows 1,3
    x = fmax_dpp<0x143,0xC,0xF>(x);   // row_bcast:31 -> rows 2,3
    float M = __int_as_float(__builtin_amdgcn_readlane(__float_as_int(x), 63));
    // lowest lane holding the max == smallest point index (lane ranges ascend)
    unsigned long long mk = __ballot(bv == M);
    int sl = (int)__builtin_ctzll(mk);
    if (lane == sl) pairbuf[i & 1][wv] = make_float4(bv, bx, by, bz);
    __syncthreads();
    float4 q0 = pairbuf[i & 1][0];
    float4 q1 = pairbuf[i & 1][1];
    float4 q2 = pairbuf[i & 1][2];
    float4 q3 = pairbuf[i & 1][3];
    float4 w01 = sel4(q0, q1);
    float4 w23 = sel4(q2, q3);
    float4 w   = sel4(w01, w23);
    cx = w.y; cy = w.z; cz = w.w;           // uniform across block
    if (t == 0) { selx[i] = cx; sely[i] = cy; selz[i] = cz; }
  }
  __syncthreads();
  for (int i = t; i < NS; i += 256) {
    float vx = selx[i], vy = sely[i], vz = selz[i];
    size_t q = (size_t)b*3*NS + i;
    out0[q] = vx; out0[q + NS] = vy; out0[q + 2*NS] = vz;   // bit-exact copies
    size_t o = (size_t)(b*NS + i)*3;
    newxyz[o] = vx; newxyz[o+1] = vy; newxyz[o+2] = vz;
  }
}

// ---------------- Ball query: one wave per query ----------------------------
__global__ __launch_bounds__(256) void k_ballq(const float* __restrict__ xyz,
                                               const float* __restrict__ newxyz,
                                               int* __restrict__ idx) {
  const int gw = (blockIdx.x * 256 + threadIdx.x) >> 6;   // global wave = query
  const int lane = threadIdx.x & 63;
  const int b = gw >> 10;
  const int s = gw & (NS-1);
  const float* xb = xyz + (size_t)b * 3 * NPTS;
  const size_t nq = (size_t)(b*NS + s)*3;
  const float nx = newxyz[nq], ny = newxyz[nq+1], nz = newxyz[nq+2];
  const float sn = __fadd_rn(__fadd_rn(__fmul_rn(nx,nx), __fmul_rn(ny,ny)), __fmul_rn(nz,nz));
  const float R2 = (float)(0.2*0.2);
  int* out = idx + (size_t)gw * NK;
  int cnt = 0, first = 0;
  for (int c0 = 0; c0 < NPTS; c0 += 64) {
    int n = c0 + lane;
    float x = xb[n], y = xb[NPTS+n], z = xb[2*NPTS+n];
    float sx = __fadd_rn(__fadd_rn(__fmul_rn(x,x), __fmul_rn(y,y)), __fmul_rn(z,z));
    float dt = __fadd_rn(__fadd_rn(__fmul_rn(nx,x), __fmul_rn(ny,y)), __fmul_rn(nz,z));
    float sqr = __fsub_rn(__fadd_rn(sn, sx), __fmul_rn(2.0f, dt));
    bool inr = (sqr <= R2);                 // kept iff NOT (sqr > r^2)
    unsigned long long m = __ballot(inr);
    if (m != 0ull) {
      if (cnt == 0) first = c0 + (int)__builtin_ctzll(m);
      int rank = __popcll(m & ((1ull << lane) - 1ull));
      int pos = cnt + rank;
      if (inr && pos < NK) out[pos] = n;
      cnt += __popcll(m);
      if (cnt >= NK) break;
    }
  }
  int tot = cnt < NK ? cnt : NK;
  if (lane >= tot && lane < NK) out[lane] = first;
}

// ---------------- Layer 1: gather + 6->64 conv -----------------------------
__global__ __launch_bounds__(256) void k_layer1(const float* __restrict__ xyz,
                                                const float* __restrict__ feat,
                                                const float* __restrict__ newxyz,
                                                const int* __restrict__ idx,
                                                const float* __restrict__ w0,
                                                const float* __restrict__ b0,
                                                bf16* __restrict__ x1) {
  __shared__ float w[64*6];
  __shared__ float bias[64];
  for (int i = threadIdx.x; i < 64*6; i += 256) w[i] = w0[i];
  if (threadIdx.x < 64) bias[threadIdx.x] = b0[threadIdx.x];
  __syncthreads();
  const int col = blockIdx.x * 256 + threadIdx.x;   // (b*NS+s)*NK + k
  const int bs = col >> 5;                          // b*NS + s
  const int b  = bs >> 10;
  const int n  = idx[col];
  const float* xb = xyz  + (size_t)b*3*NPTS;
  const float* fb = feat + (size_t)b*3*NPTS;
  float in[6];
  in[0] = __fsub_rn(xb[n],        newxyz[(size_t)bs*3]);
  in[1] = __fsub_rn(xb[NPTS+n],   newxyz[(size_t)bs*3+1]);
  in[2] = __fsub_rn(xb[2*NPTS+n], newxyz[(size_t)bs*3+2]);
  in[3] = fb[n];
  in[4] = fb[NPTS+n];
  in[5] = fb[2*NPTS+n];
  #pragma unroll
  for (int o = 0; o < 64; ++o) {
    float acc = bias[o];
    #pragma unroll
    for (int c = 0; c < 6; ++c) acc = fmaf(in[c], w[o*6+c], acc);
    x1[(size_t)o*NT_COLS + col] = __float2bfloat16(acc);
  }
}

// ---------------- Per-channel sum / sumsq (bf16 intermediates) --------------
__global__ __launch_bounds__(256) void k_stats(const bf16* __restrict__ x,
                                               float* __restrict__ accum, int C) {
  const int o = blockIdx.x >> 5;
  const int chunk = blockIdx.x & 31;
  const uint4* p = (const uint4*)(x + (size_t)o*NT_COLS + (size_t)chunk*16384);
  float s = 0.f, ss = 0.f;
  #pragma unroll
  for (int it = 0; it < 8; ++it) {
    uint4 u = p[threadIdx.x + it*256];
    uint32_t wr[4] = {u.x, u.y, u.z, u.w};
    #pragma unroll
    for (int q = 0; q < 4; ++q) {
      float a  = __uint_as_float(wr[q] << 16);
      float bq = __uint_as_float(wr[q] & 0xffff0000u);
      s += a;  ss = fmaf(a, a, ss);
      s += bq; ss = fmaf(bq, bq, ss);
    }
  }
  #pragma unroll
  for (int off = 32; off; off >>= 1) { s += __shfl_xor(s, off); ss += __shfl_xor(ss, off); }
  __shared__ float ls[4], lss[4];
  const int lane = threadIdx.x & 63, wv = threadIdx.x >> 6;
  if (lane == 0) { ls[wv] = s; lss[wv] = ss; }
  __syncthreads();
  if (threadIdx.x == 0) {
    atomicAdd(&accum[o],     (ls[0]+ls[1])+(ls[2]+ls[3]));
    atomicAdd(&accum[C + o], (lss[0]+lss[1])+(lss[2]+lss[3]));
  }
}

__global__ void k_finalize(const float* __restrict__ accum,
                           const float* __restrict__ g, const float* __restrict__ beta,
                           float* __restrict__ scsh, int C) {
  int o = blockIdx.x*256 + threadIdx.x;
  if (o < C) {
    const float n = (float)NT_COLS;
    float mu  = accum[o] / n;
    float var = accum[C+o] / n - mu*mu;
    if (var < 0.f) var = 0.f;
    float rs = rsqrtf(var + 1e-5f);
    float sc = g[o] * rs;
    scsh[o]   = sc;
    scsh[C+o] = beta[o] - mu * sc;
  }
}

// ---------------- Layers 2/3: BN+ReLU(in) then 64->CO GEMM -----------------
template<int CO>
__global__ __launch_bounds__(256) void k_layerN(const bf16* __restrict__ xin,
                                                const float* __restrict__ wN,
                                                const float* __restrict__ bN,
                                                const float* __restrict__ scsh,
                                                bf16* __restrict__ xout) {
  __shared__ float w[CO*64];
  __shared__ float bias[CO];
  __shared__ float sc[64], sh[64];
  for (int i = threadIdx.x; i < CO*64; i += 256) w[i] = wN[i];
  if (threadIdx.x < CO) bias[threadIdx.x] = bN[threadIdx.x];
  if (threadIdx.x < 64) { sc[threadIdx.x] = scsh[threadIdx.x]; sh[threadIdx.x] = scsh[64+threadIdx.x]; }
  __syncthreads();
  const int col = blockIdx.x * 256 + threadIdx.x;
  float y[64];
  #pragma unroll
  for (int c = 0; c < 64; ++c) {
    float v = __bfloat162float(xin[(size_t)c*NT_COLS + col]);
    v = fmaf(v, sc[c], sh[c]);
    y[c] = fmaxf(v, 0.f);
  }
  for (int o = 0; o < CO; ++o) {
    float acc = bias[o];
    #pragma unroll
    for (int c = 0; c < 64; ++c) acc = fmaf(w[o*64+c], y[c], acc);
    xout[(size_t)o*NT_COLS + col] = __float2bfloat16(acc);
  }
}

// ---------------- Max-pool over K with final BN+ReLU (fp32 out) -------------
__global__ __launch_bounds__(256) void k_maxpool(const bf16* __restrict__ x3,
                                                 const float* __restrict__ scsh,
                                                 float* __restrict__ out1) {
  const int t = blockIdx.x * 256 + threadIdx.x;  // (b*128+o)*NS + s
  const int s  = t & (NS-1);
  const int bo = t >> 10;
  const int o  = bo & 127;
  const int b  = bo >> 7;
  const float sc = scsh[o], sh = scsh[128+o];
  const uint4* p = (const uint4*)(x3 + (size_t)o*NT_COLS + (size_t)(b*NS + s)*NK);
  float m = 0.f;   // ReLU outputs are >= 0
  #pragma unroll
  for (int it = 0; it < 4; ++it) {
    uint4 u = p[it];
    uint32_t wr[4] = {u.x, u.y, u.z, u.w};
    #pragma unroll
    for (int q = 0; q < 4; ++q) {
      float a  = __uint_as_float(wr[q] << 16);
      float bq = __uint_as_float(wr[q] & 0xffff0000u);
      a  = fmaxf(fmaf(a,  sc, sh), 0.f);
      bq = fmaxf(fmaf(bq, sc, sh), 0.f);
      m = fmaxf(m, fmaxf(a, bq));
    }
  }
  out1[t] = m;
}

extern "C" void kernel_launch(void* const* d_in, const int* in_sizes, int n_in,
                              void* d_out, int out_size, void* d_ws, size_t ws_size,
                              hipStream_t stream) {
  const float* xyz  = (const float*)d_in[0];
  const float* feat = (const float*)d_in[1];
  const float* w0 = (const float*)d_in[2];
  const float* b0 = (const float*)d_in[3];
  const float* g0 = (const float*)d_in[4];
  const float* bt0= (const float*)d_in[5];
  const float* w1 = (const float*)d_in[6];
  const float* b1 = (const float*)d_in[7];
  const float* g1 = (const float*)d_in[8];
  const float* bt1= (const float*)d_in[9];
  const float* w2 = (const float*)d_in[10];
  const float* b2 = (const float*)d_in[11];
  const float* g2 = (const float*)d_in[12];
  const float* bt2= (const float*)d_in[13];

  float* out0 = (float*)d_out;                     // (B,3,NS) fp32
  float* out1 = out0 + (size_t)NB*3*NS;            // (B,128,NS) fp32

  // Workspace layout (total 203,628,544 B ~= 194 MB):
  //   accum@0, scsh@4096, newxyz@8192(fp32), bidx@204800,
  //   x2@2301952 (64MB), x1@69410816 (64MB), x3@69410816 (128MB, aliases dead x1)
  char* ws = (char*)d_ws;
  float* accum  = (float*)(ws + 0);
  float* scsh   = (float*)(ws + 4096);
  float* newxyz = (float*)(ws + 8192);
  int*   bidx   = (int*)  (ws + 204800);
  bf16*  x2     = (bf16*) (ws + 2301952);
  bf16*  x1     = (bf16*) (ws + 69410816);
  bf16*  x3     = (bf16*) (ws + 69410816);

  k_zero <<<1, 512, 0, stream>>>(accum);

  k_fps  <<<NB,   256, 0, stream>>>(xyz, newxyz, out0);
  k_ballq<<<16384/4, 256, 0, stream>>>(xyz, newxyz, bidx);
  k_layer1<<<NT_COLS/256, 256, 0, stream>>>(xyz, feat, newxyz, bidx, w0, b0, x1);

  k_stats   <<<64*32, 256, 0, stream>>>(x1, accum + 0, 64);
  k_finalize<<<1,     256, 0, stream>>>(accum + 0, g0, bt0, scsh + 0, 64);
  k_layerN<64><<<NT_COLS/256, 256, 0, stream>>>(x1, w1, b1, scsh + 0, x2);

  k_stats   <<<64*32, 256, 0, stream>>>(x2, accum + 128, 64);
  k_finalize<<<1,     256, 0, stream>>>(accum + 128, g1, bt1, scsh + 128, 64);
  k_layerN<128><<<NT_COLS/256, 256, 0, stream>>>(x2, w2, b2, scsh + 128, x3);

  k_stats   <<<128*32, 256, 0, stream>>>(x3, accum + 256, 128);
  k_finalize<<<1,      256, 0, stream>>>(accum + 256, g2, bt2, scsh + 256, 128);
  k_maxpool <<<(NB*128*NS)/256, 256, 0, stream>>>(x3, scsh + 256, out1);
}

// Round 7
// 949.230 us; speedup vs baseline: 1.3460x; 1.3460x over previous
//
#include <hip/hip_runtime.h>
#include <hip/hip_bf16.h>
#include <stdint.h>

#define NB 16
#define NPTS 4096
#define NS 1024
#define NK 32
#define NT_COLS (NB*NS*NK)   // 524288 columns (b*NS+s)*NK + k
#define NBUCK 64             // stat-accumulator buckets (contention spread)

typedef __hip_bfloat16 bf16;
typedef __attribute__((ext_vector_type(8))) short short8;   // 8 bf16 (4 VGPRs)
typedef __attribute__((ext_vector_type(4))) float floatx4;  // MFMA C/D

__device__ __forceinline__ unsigned short f2bf_bits(float v) {
  bf16 b = __float2bfloat16(v);
  return *(unsigned short*)&b;
}

__global__ void k_zero(float* __restrict__ p) {
  p[blockIdx.x*256 + threadIdx.x] = 0.f;   // grid sized exactly
}

// DPP-shifted fmax (verified gfx950, R5). Disabled/OOB lanes keep old=x.
template<int CTRL, int RM, int BM>
__device__ __forceinline__ float fmax_dpp(float x) {
  int o = __builtin_amdgcn_update_dpp(__float_as_int(x), __float_as_int(x),
                                      CTRL, RM, BM, false);
  return fmaxf(x, __int_as_float(o));
}
// DPP-shifted add with zero-fill (for sums): row_shr chain, total lands on
// lane 15 of each 16-lane row.
template<int CTRL>
__device__ __forceinline__ float add_dpp(float x) {
  int o = __builtin_amdgcn_update_dpp(0, __float_as_int(x), CTRL, 0xF, 0xF, true);
  return __fadd_rn(x, __int_as_float(o));
}

// ---------------- FPS: EXACT R5 version (measured 586 us, stable) -----------
__global__ __launch_bounds__(256) void k_fps(const float* __restrict__ xyz,
                                             float* __restrict__ newxyz,
                                             float* __restrict__ out0) {
  __shared__ float xs[NPTS], ys[NPTS], zs[NPTS];
  __shared__ float2 pair[2][4];   // double-buffered (value, idx-bits) per wave
  const int b = blockIdx.x;
  const int t = threadIdx.x;
  const float* p = xyz + (size_t)b * 3 * NPTS;
  for (int i = t; i < NPTS; i += 256) {
    xs[i] = p[i];
    ys[i] = p[NPTS + i];
    zs[i] = p[2*NPTS + i];
  }
  __syncthreads();
  float px[16], py[16], pz[16], dist[16];
  const int p0 = t * 16;
  #pragma unroll
  for (int j = 0; j < 16; ++j) {
    px[j]=xs[p0+j]; py[j]=ys[p0+j]; pz[j]=zs[p0+j]; dist[j]=1e10f;
  }
  const int lane = t & 63, wv = t >> 6;
  int cur = 0;
  for (int i = 0; i < NS; ++i) {
    if (t == 0) {
      float cx = xs[cur], cy = ys[cur], cz = zs[cur];
      size_t o = (size_t)(b*NS + i)*3;
      newxyz[o] = cx; newxyz[o+1] = cy; newxyz[o+2] = cz;
      size_t q = (size_t)b*3*NS + i;
      out0[q] = cx; out0[q + NS] = cy; out0[q + 2*NS] = cz;  // bit-exact copy
    }
    if (i == NS-1) break;
    float cx = xs[cur], cy = ys[cur], cz = zs[cur];
    float bv = -1.0f; int bi = p0;
    #pragma unroll
    for (int j = 0; j < 16; ++j) {
      float dx = __fsub_rn(px[j], cx);
      float dy = __fsub_rn(py[j], cy);
      float dz = __fsub_rn(pz[j], cz);
      float d  = __fadd_rn(__fadd_rn(__fmul_rn(dx,dx), __fmul_rn(dy,dy)), __fmul_rn(dz,dz));
      float nd = fminf(dist[j], d);
      dist[j] = nd;
      if (nd > bv) { bv = nd; bi = p0 + j; }   // strict > => first occurrence
    }
    float x = bv;
    x = fmax_dpp<0x111,0xF,0xF>(x);   // row_shr:1
    x = fmax_dpp<0x112,0xF,0xF>(x);   // row_shr:2
    x = fmax_dpp<0x114,0xF,0xF>(x);   // row_shr:4
    x = fmax_dpp<0x118,0xF,0xF>(x);   // row_shr:8
    x = fmax_dpp<0x142,0xA,0xF>(x);   // row_bcast:15 -> rows 1,3
    x = fmax_dpp<0x143,0xC,0xF>(x);   // row_bcast:31 -> rows 2,3
    float M = __int_as_float(__builtin_amdgcn_readlane(__float_as_int(x), 63));
    unsigned long long mk = __ballot(bv == M);
    int sl  = (int)__builtin_ctzll(mk);
    int wbi = __builtin_amdgcn_readlane(bi, sl);
    if ((t & 63) == 0) pair[i & 1][wv] = make_float2(M, __int_as_float(wbi));
    __syncthreads();
    const float4* pb = (const float4*)&pair[i & 1][0];
    float4 q01 = pb[0], q23 = pb[1];
    float bestv = q01.x; int besti = __float_as_int(q01.y);
    if (q01.z > bestv) { bestv = q01.z; besti = __float_as_int(q01.w); }
    if (q23.x > bestv) { bestv = q23.x; besti = __float_as_int(q23.y); }
    if (q23.z > bestv) { bestv = q23.z; besti = __float_as_int(q23.w); }
    cur = besti;
  }
}

// ---------------- Ball query: one wave per query ----------------------------
__global__ __launch_bounds__(256) void k_ballq(const float* __restrict__ xyz,
                                               const float* __restrict__ newxyz,
                                               int* __restrict__ idx) {
  const int gw = (blockIdx.x * 256 + threadIdx.x) >> 6;
  const int lane = threadIdx.x & 63;
  const int b = gw >> 10;
  const int s = gw & (NS-1);
  const float* xb = xyz + (size_t)b * 3 * NPTS;
  const size_t nq = (size_t)(b*NS + s)*3;
  const float nx = newxyz[nq], ny = newxyz[nq+1], nz = newxyz[nq+2];
  const float sn = __fadd_rn(__fadd_rn(__fmul_rn(nx,nx), __fmul_rn(ny,ny)), __fmul_rn(nz,nz));
  const float R2 = (float)(0.2*0.2);
  int* out = idx + (size_t)gw * NK;
  int cnt = 0, first = 0;
  for (int c0 = 0; c0 < NPTS; c0 += 64) {
    int n = c0 + lane;
    float x = xb[n], y = xb[NPTS+n], z = xb[2*NPTS+n];
    float sx = __fadd_rn(__fadd_rn(__fmul_rn(x,x), __fmul_rn(y,y)), __fmul_rn(z,z));
    float dt = __fadd_rn(__fadd_rn(__fmul_rn(nx,x), __fmul_rn(ny,y)), __fmul_rn(nz,z));
    float sqr = __fsub_rn(__fadd_rn(sn, sx), __fmul_rn(2.0f, dt));
    bool inr = (sqr <= R2);
    unsigned long long m = __ballot(inr);
    if (m != 0ull) {
      if (cnt == 0) first = c0 + (int)__builtin_ctzll(m);
      int rank = __popcll(m & ((1ull << lane) - 1ull));
      int pos = cnt + rank;
      if (inr && pos < NK) out[pos] = n;
      cnt += __popcll(m);
      if (cnt >= NK) break;
    }
  }
  int tot = cnt < NK ? cnt : NK;
  if (lane >= tot && lane < NK) out[lane] = first;
}

// ---------------- Layer 1: gather + 6->64 conv -----------------------------
__global__ __launch_bounds__(256) void k_layer1(const float* __restrict__ xyz,
                                                const float* __restrict__ feat,
                                                const float* __restrict__ newxyz,
                                                const int* __restrict__ idx,
                                                const float* __restrict__ w0,
                                                const float* __restrict__ b0,
                                                bf16* __restrict__ x1) {
  __shared__ float w[64*6];
  __shared__ float bias[64];
  for (int i = threadIdx.x; i < 64*6; i += 256) w[i] = w0[i];
  if (threadIdx.x < 64) bias[threadIdx.x] = b0[threadIdx.x];
  __syncthreads();
  const int col = blockIdx.x * 256 + threadIdx.x;
  const int bs = col >> 5;
  const int b  = bs >> 10;
  const int n  = idx[col];
  const float* xb = xyz  + (size_t)b*3*NPTS;
  const float* fb = feat + (size_t)b*3*NPTS;
  float in[6];
  in[0] = __fsub_rn(xb[n],        newxyz[(size_t)bs*3]);
  in[1] = __fsub_rn(xb[NPTS+n],   newxyz[(size_t)bs*3+1]);
  in[2] = __fsub_rn(xb[2*NPTS+n], newxyz[(size_t)bs*3+2]);
  in[3] = fb[n];
  in[4] = fb[NPTS+n];
  in[5] = fb[2*NPTS+n];
  #pragma unroll
  for (int o = 0; o < 64; ++o) {
    float acc = bias[o];
    #pragma unroll
    for (int c = 0; c < 6; ++c) acc = fmaf(in[c], w[o*6+c], acc);
    x1[(size_t)o*NT_COLS + col] = __float2bfloat16(acc);
  }
}

// ---------------- Per-channel sum/sumsq for x1 (bucketed accum) -------------
__global__ __launch_bounds__(256) void k_stats(const bf16* __restrict__ x,
                                               float* __restrict__ accum, int C) {
  const int o = blockIdx.x >> 5;
  const int chunk = blockIdx.x & 31;
  const uint4* p = (const uint4*)(x + (size_t)o*NT_COLS + (size_t)chunk*16384);
  float s = 0.f, ss = 0.f;
  #pragma unroll
  for (int it = 0; it < 8; ++it) {
    uint4 u = p[threadIdx.x + it*256];
    uint32_t wr[4] = {u.x, u.y, u.z, u.w};
    #pragma unroll
    for (int q = 0; q < 4; ++q) {
      float a  = __uint_as_float(wr[q] << 16);
      float bq = __uint_as_float(wr[q] & 0xffff0000u);
      s += a;  ss = fmaf(a, a, ss);
      s += bq; ss = fmaf(bq, bq, ss);
    }
  }
  #pragma unroll
  for (int off = 32; off; off >>= 1) { s += __shfl_xor(s, off); ss += __shfl_xor(ss, off); }
  __shared__ float ls[4], lss[4];
  const int lane = threadIdx.x & 63, wv = threadIdx.x >> 6;
  if (lane == 0) { ls[wv] = s; lss[wv] = ss; }
  __syncthreads();
  if (threadIdx.x == 0) {
    float* dst = accum + (size_t)(blockIdx.x & (NBUCK-1))*(2*C);
    atomicAdd(&dst[o],     (ls[0]+ls[1])+(ls[2]+ls[3]));
    atomicAdd(&dst[C + o], (lss[0]+lss[1])+(lss[2]+lss[3]));
  }
}

// ---------------- finalize: sum buckets -> sc/sh ---------------------------
__global__ void k_finalize(const float* __restrict__ accum,
                           const float* __restrict__ g, const float* __restrict__ beta,
                           float* __restrict__ scsh, int C) {
  int o = threadIdx.x;
  if (o < C) {
    float s = 0.f, ss = 0.f;
    for (int bkt = 0; bkt < NBUCK; ++bkt) {
      s  += accum[(size_t)bkt*(2*C) + o];
      ss += accum[(size_t)bkt*(2*C) + C + o];
    }
    const float n = (float)NT_COLS;
    float mu  = s / n;
    float var = ss / n - mu*mu;
    if (var < 0.f) var = 0.f;
    float rs = rsqrtf(var + 1e-5f);
    float sc = g[o] * rs;
    scsh[o]   = sc;
    scsh[C+o] = beta[o] - mu * sc;
  }
}

// ---------------- Layers 2/3: MFMA GEMM + fused stats ----------------------
// out[o][col] = sum_c W[o][c] * relu(bn(xin[c][col])) + bias[o]
// mfma_f32_16x16x32_bf16 layouts (guide §3, m89/m120-verified):
//   A[m][k]: m=lane&15, k=(lane>>4)*8+j   (j=0..7 regs)
//   B[k][n]: n=lane&15, k=(lane>>4)*8+j
//   C/D:     col=lane&15, row=(lane>>4)*4+reg
#define XT_STRIDE 72   // bf16 elems; 144 B row -> b128-aligned, ~4-way conflicts
template<int CO>
__global__ __launch_bounds__(256) void k_layerN_mfma(
    const bf16*  __restrict__ xin,   // [64][NT_COLS] raw conv+bias of prev layer
    const float* __restrict__ wN,    // [CO][64]
    const float* __restrict__ bN,    // [CO]
    const float* __restrict__ scsh,  // sc[64], sh[64] for input BN
    float*       __restrict__ accum, // [NBUCK][2*CO] bucketed stats
    bf16*        __restrict__ xout) {// [CO][NT_COLS]
  constexpr int RT = CO/16;
  __shared__ short xT[256*XT_STRIDE];       // BN'd input, transposed [col][c]
  __shared__ float sc_s[64], sh_s[64], bias_s[CO];
  const int t = threadIdx.x;
  const int col0 = blockIdx.x * 256;
  if (t < 64) { sc_s[t] = scsh[t]; sh_s[t] = scsh[64+t]; }
  if (t < CO) bias_s[t] = bN[t];
  __syncthreads();
  // ---- stage: thread t = column col0+t; BN+ReLU, pack 8 c at a time ----
  {
    const int col = col0 + t;
    #pragma unroll
    for (int c0 = 0; c0 < 64; c0 += 8) {
      short8 pk;
      #pragma unroll
      for (int j = 0; j < 8; ++j) {
        float v = __bfloat162float(xin[(size_t)(c0+j)*NT_COLS + col]);
        v = fmaxf(fmaf(v, sc_s[c0+j], sh_s[c0+j]), 0.f);
        pk[j] = (short)f2bf_bits(v);
      }
      *((short8*)&xT[t*XT_STRIDE + c0]) = pk;   // 16 B aligned
    }
  }
  __syncthreads();
  const int lane = t & 63, wv = t >> 6;
  const int qd = lane >> 4, ln = lane & 15;
  // ---- A fragments: W rows, fp32 global -> bf16 ----
  short8 A[RT][2];
  #pragma unroll
  for (int rt = 0; rt < RT; ++rt) {
    #pragma unroll
    for (int kh = 0; kh < 2; ++kh) {
      const float* wp = wN + (size_t)(rt*16 + ln)*64 + kh*32 + qd*8;
      float4 f0 = *(const float4*)wp;
      float4 f1 = *(const float4*)(wp + 4);
      short8 a;
      a[0]=(short)f2bf_bits(f0.x); a[1]=(short)f2bf_bits(f0.y);
      a[2]=(short)f2bf_bits(f0.z); a[3]=(short)f2bf_bits(f0.w);
      a[4]=(short)f2bf_bits(f1.x); a[5]=(short)f2bf_bits(f1.y);
      a[6]=(short)f2bf_bits(f1.z); a[7]=(short)f2bf_bits(f1.w);
      A[rt][kh] = a;
    }
  }
  // ---- MFMA main: wave handles cols [wv*64, wv*64+64) = 4 col-tiles ----
  floatx4 acc[RT][4];
  #pragma unroll
  for (int rt = 0; rt < RT; ++rt)
    #pragma unroll
    for (int ct = 0; ct < 4; ++ct)
      acc[rt][ct] = (floatx4)0.f;
  #pragma unroll
  for (int ct = 0; ct < 4; ++ct) {
    const int coll = wv*64 + ct*16 + ln;    // B n-index column
    short8 B0 = *((const short8*)&xT[coll*XT_STRIDE + qd*8]);        // k=qd*8+j
    short8 B1 = *((const short8*)&xT[coll*XT_STRIDE + 32 + qd*8]);   // k=32+...
    #pragma unroll
    for (int rt = 0; rt < RT; ++rt) {
      acc[rt][ct] = __builtin_amdgcn_mfma_f32_16x16x32_bf16(A[rt][0], B0, acc[rt][ct], 0,0,0);
      acc[rt][ct] = __builtin_amdgcn_mfma_f32_16x16x32_bf16(A[rt][1], B1, acc[rt][ct], 0,0,0);
    }
  }
  // ---- epilogue: bias, store bf16, fused per-channel stats ----
  float* dst = accum + (size_t)(blockIdx.x & (NBUCK-1))*(2*CO);
  #pragma unroll
  for (int rt = 0; rt < RT; ++rt) {
    float s[4]  = {0.f,0.f,0.f,0.f};
    float sq[4] = {0.f,0.f,0.f,0.f};
    #pragma unroll
    for (int ct = 0; ct < 4; ++ct) {
      const int col = col0 + wv*64 + ct*16 + ln;
      #pragma unroll
      for (int r = 0; r < 4; ++r) {
        const int o = rt*16 + qd*4 + r;     // C/D row = channel
        float v = acc[rt][ct][r] + bias_s[o];
        xout[(size_t)o*NT_COLS + col] = __float2bfloat16(v);
        s[r] += v; sq[r] = fmaf(v, v, sq[r]);
      }
    }
    #pragma unroll
    for (int r = 0; r < 4; ++r) {
      float a = s[r], q = sq[r];
      a = add_dpp<0x111>(a); a = add_dpp<0x112>(a);
      a = add_dpp<0x114>(a); a = add_dpp<0x118>(a);
      q = add_dpp<0x111>(q); q = add_dpp<0x112>(q);
      q = add_dpp<0x114>(q); q = add_dpp<0x118>(q);
      if (ln == 15) {                        // lane 15 of each 16-lane row
        const int o = rt*16 + qd*4 + r;
        atomicAdd(&dst[o], a);
        atomicAdd(&dst[CO + o], q);
      }
    }
  }
}

// ---------------- Max-pool over K with final BN+ReLU (fp32 out) -------------
__global__ __launch_bounds__(256) void k_maxpool(const bf16* __restrict__ x3,
                                                 const float* __restrict__ scsh,
                                                 float* __restrict__ out1) {
  const int t = blockIdx.x * 256 + threadIdx.x;  // (b*128+o)*NS + s
  const int s  = t & (NS-1);
  const int bo = t >> 10;
  const int o  = bo & 127;
  const int b  = bo >> 7;
  const float sc = scsh[o], sh = scsh[128+o];
  const uint4* p = (const uint4*)(x3 + (size_t)o*NT_COLS + (size_t)(b*NS + s)*NK);
  float m = 0.f;   // ReLU outputs are >= 0
  #pragma unroll
  for (int it = 0; it < 4; ++it) {
    uint4 u = p[it];
    uint32_t wr[4] = {u.x, u.y, u.z, u.w};
    #pragma unroll
    for (int q = 0; q < 4; ++q) {
      float a  = __uint_as_float(wr[q] << 16);
      float bq = __uint_as_float(wr[q] & 0xffff0000u);
      a  = fmaxf(fmaf(a,  sc, sh), 0.f);
      bq = fmaxf(fmaf(bq, sc, sh), 0.f);
      m = fmaxf(m, fmaxf(a, bq));
    }
  }
  out1[t] = m;
}

extern "C" void kernel_launch(void* const* d_in, const int* in_sizes, int n_in,
                              void* d_out, int out_size, void* d_ws, size_t ws_size,
                              hipStream_t stream) {
  const float* xyz  = (const float*)d_in[0];
  const float* feat = (const float*)d_in[1];
  const float* w0 = (const float*)d_in[2];
  const float* b0 = (const float*)d_in[3];
  const float* g0 = (const float*)d_in[4];
  const float* bt0= (const float*)d_in[5];
  const float* w1 = (const float*)d_in[6];
  const float* b1 = (const float*)d_in[7];
  const float* g1 = (const float*)d_in[8];
  const float* bt1= (const float*)d_in[9];
  const float* w2 = (const float*)d_in[10];
  const float* b2 = (const float*)d_in[11];
  const float* g2 = (const float*)d_in[12];
  const float* bt2= (const float*)d_in[13];

  float* out0 = (float*)d_out;                     // (B,3,NS) fp32
  float* out1 = out0 + (size_t)NB*3*NS;            // (B,128,NS) fp32

  // Workspace layout (total 203,753,472 B ~= 194 MB):
  //   accum  @ 0        : 32768 floats (l1: 64x128, l2: 64x128, l3: 64x256)
  //   scsh   @ 131072   : 512 floats (l1:0, l2:128, l3:256)
  //   newxyz @ 133120   : 192 KB fp32
  //   bidx   @ 329728   : 2 MB int32
  //   x2     @ 2426880  : 64 MB bf16
  //   x1     @ 69535744 : 64 MB bf16
  //   x3     @ 69535744 : 128 MB bf16 (aliases dead x1)
  char* ws = (char*)d_ws;
  float* accum  = (float*)(ws + 0);
  float* acc_l1 = accum;                 // NBUCK x 128
  float* acc_l2 = accum + 8192;          // NBUCK x 128
  float* acc_l3 = accum + 16384;         // NBUCK x 256
  float* scsh   = (float*)(ws + 131072);
  float* newxyz = (float*)(ws + 133120);
  int*   bidx   = (int*)  (ws + 329728);
  bf16*  x2     = (bf16*) (ws + 2426880);
  bf16*  x1     = (bf16*) (ws + 69535744);
  bf16*  x3     = (bf16*) (ws + 69535744);

  k_zero <<<128, 256, 0, stream>>>(accum);   // 32768 floats

  k_fps  <<<NB,   256, 0, stream>>>(xyz, newxyz, out0);
  k_ballq<<<16384/4, 256, 0, stream>>>(xyz, newxyz, bidx);
  k_layer1<<<NT_COLS/256, 256, 0, stream>>>(xyz, feat, newxyz, bidx, w0, b0, x1);

  k_stats   <<<64*32, 256, 0, stream>>>(x1, acc_l1, 64);
  k_finalize<<<1,     256, 0, stream>>>(acc_l1, g0, bt0, scsh + 0, 64);

  k_layerN_mfma<64><<<NT_COLS/256, 256, 0, stream>>>(x1, w1, b1, scsh + 0, acc_l2, x2);
  k_finalize<<<1,     256, 0, stream>>>(acc_l2, g1, bt1, scsh + 128, 64);

  k_layerN_mfma<128><<<NT_COLS/256, 256, 0, stream>>>(x2, w2, b2, scsh + 128, acc_l3, x3);
  k_finalize<<<1,     256, 0, stream>>>(acc_l3, g2, bt2, scsh + 256, 128);

  k_maxpool <<<(NB*128*NS)/256, 256, 0, stream>>>(x3, scsh + 256, out1);
}

// Round 8
// 908.915 us; speedup vs baseline: 1.4057x; 1.0444x over previous
//
#include <hip/hip_runtime.h>
#include <hip/hip_bf16.h>
#include <stdint.h>

#define NB 16
#define NPTS 4096
#define NS 1024
#define NK 32
#define NT_COLS (NB*NS*NK)   // 524288 columns (b*NS+s)*NK + k
#define NBUCK 64             // stat-accumulator buckets

typedef __hip_bfloat16 bf16;
typedef __attribute__((ext_vector_type(8))) short short8;   // 8 bf16 (4 VGPRs)
typedef __attribute__((ext_vector_type(4))) float floatx4;  // MFMA C/D

__device__ __forceinline__ unsigned short f2bf_bits(float v) {
  bf16 b = __float2bfloat16(v);
  return *(unsigned short*)&b;
}

__global__ void k_zero(float* __restrict__ p) {
  p[blockIdx.x*256 + threadIdx.x] = 0.f;
}

// DPP-shifted fmax (verified gfx950, R5/R7). Inactive/OOB src lanes keep old=x.
template<int CTRL, int RM, int BM>
__device__ __forceinline__ float fmax_dpp(float x) {
  int o = __builtin_amdgcn_update_dpp(__float_as_int(x), __float_as_int(x),
                                      CTRL, RM, BM, false);
  return fmaxf(x, __int_as_float(o));
}
// DPP-shifted add with zero-fill; 4-step chain sums 16-lane row onto lane 15.
template<int CTRL>
__device__ __forceinline__ float add_dpp(float x) {
  int o = __builtin_amdgcn_update_dpp(0, __float_as_int(x), CTRL, 0xF, 0xF, true);
  return __fadd_rn(x, __int_as_float(o));
}

// ---------------- FPS: R5 structure + deferred global writes ----------------
// ONLY delta vs R5 (586 us measured): per-iteration t0 global stores replaced
// by LDS sel-array writes (kills the vmcnt(0) drain at every __syncthreads);
// bulk global write after the loop. Everything else byte-identical.
__global__ __launch_bounds__(256) void k_fps(const float* __restrict__ xyz,
                                             float* __restrict__ newxyz,
                                             float* __restrict__ out0) {
  __shared__ float xs[NPTS], ys[NPTS], zs[NPTS];
  __shared__ float selx[NS], sely[NS], selz[NS];
  __shared__ float2 pair[2][4];   // double-buffered (value, idx-bits) per wave
  const int b = blockIdx.x;
  const int t = threadIdx.x;
  const float* p = xyz + (size_t)b * 3 * NPTS;
  for (int i = t; i < NPTS; i += 256) {
    xs[i] = p[i];
    ys[i] = p[NPTS + i];
    zs[i] = p[2*NPTS + i];
  }
  __syncthreads();
  float px[16], py[16], pz[16], dist[16];
  const int p0 = t * 16;
  #pragma unroll
  for (int j = 0; j < 16; ++j) {
    px[j]=xs[p0+j]; py[j]=ys[p0+j]; pz[j]=zs[p0+j]; dist[j]=1e10f;
  }
  const int lane = t & 63, wv = t >> 6;
  int cur = 0;
  for (int i = 0; i < NS; ++i) {
    float cx = xs[cur], cy = ys[cur], cz = zs[cur];
    if (t == 0) { selx[i] = cx; sely[i] = cy; selz[i] = cz; }  // LDS, no vmcnt
    if (i == NS-1) break;
    float bv = -1.0f; int bi = p0;
    #pragma unroll
    for (int j = 0; j < 16; ++j) {
      float dx = __fsub_rn(px[j], cx);
      float dy = __fsub_rn(py[j], cy);
      float dz = __fsub_rn(pz[j], cz);
      float d  = __fadd_rn(__fadd_rn(__fmul_rn(dx,dx), __fmul_rn(dy,dy)), __fmul_rn(dz,dz));
      float nd = fminf(dist[j], d);
      dist[j] = nd;
      if (nd > bv) { bv = nd; bi = p0 + j; }   // strict > => first occurrence
    }
    float x = bv;
    x = fmax_dpp<0x111,0xF,0xF>(x);   // row_shr:1
    x = fmax_dpp<0x112,0xF,0xF>(x);   // row_shr:2
    x = fmax_dpp<0x114,0xF,0xF>(x);   // row_shr:4
    x = fmax_dpp<0x118,0xF,0xF>(x);   // row_shr:8
    x = fmax_dpp<0x142,0xA,0xF>(x);   // row_bcast:15 -> rows 1,3
    x = fmax_dpp<0x143,0xC,0xF>(x);   // row_bcast:31 -> rows 2,3
    float M = __int_as_float(__builtin_amdgcn_readlane(__float_as_int(x), 63));
    unsigned long long mk = __ballot(bv == M);
    int sl  = (int)__builtin_ctzll(mk);
    int wbi = __builtin_amdgcn_readlane(bi, sl);
    if ((t & 63) == 0) pair[i & 1][wv] = make_float2(M, __int_as_float(wbi));
    __syncthreads();
    const float4* pb = (const float4*)&pair[i & 1][0];
    float4 q01 = pb[0], q23 = pb[1];
    float bestv = q01.x; int besti = __float_as_int(q01.y);
    if (q01.z > bestv) { bestv = q01.z; besti = __float_as_int(q01.w); }
    if (q23.x > bestv) { bestv = q23.x; besti = __float_as_int(q23.y); }
    if (q23.z > bestv) { bestv = q23.z; besti = __float_as_int(q23.w); }
    cur = besti;
  }
  __syncthreads();
  for (int i = t; i < NS; i += 256) {
    float vx = selx[i], vy = sely[i], vz = selz[i];
    size_t q = (size_t)b*3*NS + i;
    out0[q] = vx; out0[q + NS] = vy; out0[q + 2*NS] = vz;   // bit-exact copies
    size_t o = (size_t)(b*NS + i)*3;
    newxyz[o] = vx; newxyz[o+1] = vy; newxyz[o+2] = vz;
  }
}

// ---------------- Ball query: one wave per query ----------------------------
__global__ __launch_bounds__(256) void k_ballq(const float* __restrict__ xyz,
                                               const float* __restrict__ newxyz,
                                               int* __restrict__ idx) {
  const int gw = (blockIdx.x * 256 + threadIdx.x) >> 6;
  const int lane = threadIdx.x & 63;
  const int b = gw >> 10;
  const int s = gw & (NS-1);
  const float* xb = xyz + (size_t)b * 3 * NPTS;
  const size_t nq = (size_t)(b*NS + s)*3;
  const float nx = newxyz[nq], ny = newxyz[nq+1], nz = newxyz[nq+2];
  const float sn = __fadd_rn(__fadd_rn(__fmul_rn(nx,nx), __fmul_rn(ny,ny)), __fmul_rn(nz,nz));
  const float R2 = (float)(0.2*0.2);
  int* out = idx + (size_t)gw * NK;
  int cnt = 0, first = 0;
  for (int c0 = 0; c0 < NPTS; c0 += 64) {
    int n = c0 + lane;
    float x = xb[n], y = xb[NPTS+n], z = xb[2*NPTS+n];
    float sx = __fadd_rn(__fadd_rn(__fmul_rn(x,x), __fmul_rn(y,y)), __fmul_rn(z,z));
    float dt = __fadd_rn(__fadd_rn(__fmul_rn(nx,x), __fmul_rn(ny,y)), __fmul_rn(nz,z));
    float sqr = __fsub_rn(__fadd_rn(sn, sx), __fmul_rn(2.0f, dt));
    bool inr = (sqr <= R2);
    unsigned long long m = __ballot(inr);
    if (m != 0ull) {
      if (cnt == 0) first = c0 + (int)__builtin_ctzll(m);
      int rank = __popcll(m & ((1ull << lane) - 1ull));
      int pos = cnt + rank;
      if (inr && pos < NK) out[pos] = n;
      cnt += __popcll(m);
      if (cnt >= NK) break;
    }
  }
  int tot = cnt < NK ? cnt : NK;
  if (lane >= tot && lane < NK) out[lane] = first;
}

// ---------------- Layer 1: gather + 6->64 conv -----------------------------
__global__ __launch_bounds__(256) void k_layer1(const float* __restrict__ xyz,
                                                const float* __restrict__ feat,
                                                const float* __restrict__ newxyz,
                                                const int* __restrict__ idx,
                                                const float* __restrict__ w0,
                                                const float* __restrict__ b0,
                                                bf16* __restrict__ x1) {
  __shared__ float w[64*6];
  __shared__ float bias[64];
  for (int i = threadIdx.x; i < 64*6; i += 256) w[i] = w0[i];
  if (threadIdx.x < 64) bias[threadIdx.x] = b0[threadIdx.x];
  __syncthreads();
  const int col = blockIdx.x * 256 + threadIdx.x;
  const int bs = col >> 5;
  const int b  = bs >> 10;
  const int n  = idx[col];
  const float* xb = xyz  + (size_t)b*3*NPTS;
  const float* fb = feat + (size_t)b*3*NPTS;
  float in[6];
  in[0] = __fsub_rn(xb[n],        newxyz[(size_t)bs*3]);
  in[1] = __fsub_rn(xb[NPTS+n],   newxyz[(size_t)bs*3+1]);
  in[2] = __fsub_rn(xb[2*NPTS+n], newxyz[(size_t)bs*3+2]);
  in[3] = fb[n];
  in[4] = fb[NPTS+n];
  in[5] = fb[2*NPTS+n];
  #pragma unroll
  for (int o = 0; o < 64; ++o) {
    float acc = bias[o];
    #pragma unroll
    for (int c = 0; c < 6; ++c) acc = fmaf(in[c], w[o*6+c], acc);
    x1[(size_t)o*NT_COLS + col] = __float2bfloat16(acc);
  }
}

// ---------------- Per-channel sum/sumsq for x1 (bucketed accum) -------------
__global__ __launch_bounds__(256) void k_stats(const bf16* __restrict__ x,
                                               float* __restrict__ accum, int C) {
  const int o = blockIdx.x >> 5;
  const int chunk = blockIdx.x & 31;
  const uint4* p = (const uint4*)(x + (size_t)o*NT_COLS + (size_t)chunk*16384);
  float s = 0.f, ss = 0.f;
  #pragma unroll
  for (int it = 0; it < 8; ++it) {
    uint4 u = p[threadIdx.x + it*256];
    uint32_t wr[4] = {u.x, u.y, u.z, u.w};
    #pragma unroll
    for (int q = 0; q < 4; ++q) {
      float a  = __uint_as_float(wr[q] << 16);
      float bq = __uint_as_float(wr[q] & 0xffff0000u);
      s += a;  ss = fmaf(a, a, ss);
      s += bq; ss = fmaf(bq, bq, ss);
    }
  }
  #pragma unroll
  for (int off = 32; off; off >>= 1) { s += __shfl_xor(s, off); ss += __shfl_xor(ss, off); }
  __shared__ float ls[4], lss[4];
  const int lane = threadIdx.x & 63, wv = threadIdx.x >> 6;
  if (lane == 0) { ls[wv] = s; lss[wv] = ss; }
  __syncthreads();
  if (threadIdx.x == 0) {
    float* dst = accum + (size_t)(blockIdx.x & (NBUCK-1))*(2*C);
    atomicAdd(&dst[o],     (ls[0]+ls[1])+(ls[2]+ls[3]));
    atomicAdd(&dst[C + o], (lss[0]+lss[1])+(lss[2]+lss[3]));
  }
}

// ---------------- finalize: sum buckets -> sc/sh ---------------------------
__global__ void k_finalize(const float* __restrict__ accum,
                           const float* __restrict__ g, const float* __restrict__ beta,
                           float* __restrict__ scsh, int C) {
  int o = threadIdx.x;
  if (o < C) {
    float s = 0.f, ss = 0.f;
    for (int bkt = 0; bkt < NBUCK; ++bkt) {
      s  += accum[(size_t)bkt*(2*C) + o];
      ss += accum[(size_t)bkt*(2*C) + C + o];
    }
    const float n = (float)NT_COLS;
    float mu  = s / n;
    float var = ss / n - mu*mu;
    if (var < 0.f) var = 0.f;
    float rs = rsqrtf(var + 1e-5f);
    float sc = g[o] * rs;
    scsh[o]   = sc;
    scsh[C+o] = beta[o] - mu * sc;
  }
}

// ---------------- Layers 2/3: MFMA GEMM + fused stats (+ fused max) --------
// out[o][col] = sum_c W[o][c] * relu(bn(xin[c][col])) + bias[o]
// POOL: instead of storing xout, store per-(o, bs) max over the K=32 columns
// (valid final-BN commute since sc3 = g*rsqrt(var+eps) > 0 with g=1).
#define XT_STRIDE 72   // bf16 elems; 144 B row -> b128-aligned
template<int CO, bool POOL>
__global__ __launch_bounds__(256) void k_layerN_mfma(
    const bf16*  __restrict__ xin,   // [64][NT_COLS] raw conv+bias of prev layer
    const float* __restrict__ wN,    // [CO][64]
    const float* __restrict__ bN,    // [CO]
    const float* __restrict__ scsh,  // sc[64], sh[64] for input BN
    float*       __restrict__ accum, // [NBUCK][2*CO] bucketed stats
    bf16*        __restrict__ xout,  // [CO][NT_COLS]      (if !POOL)
    float*       __restrict__ mx) {  // [CO][NT_COLS/NK]   (if POOL)
  constexpr int RT = CO/16;
  __shared__ short xT[256*XT_STRIDE];       // BN'd input, transposed [col][c]
  __shared__ float sc_s[64], sh_s[64], bias_s[CO];
  const int t = threadIdx.x;
  const int col0 = blockIdx.x * 256;
  if (t < 64) { sc_s[t] = scsh[t]; sh_s[t] = scsh[64+t]; }
  if (t < CO) bias_s[t] = bN[t];
  __syncthreads();
  {
    const int col = col0 + t;
    #pragma unroll
    for (int c0 = 0; c0 < 64; c0 += 8) {
      short8 pk;
      #pragma unroll
      for (int j = 0; j < 8; ++j) {
        float v = __bfloat162float(xin[(size_t)(c0+j)*NT_COLS + col]);
        v = fmaxf(fmaf(v, sc_s[c0+j], sh_s[c0+j]), 0.f);
        pk[j] = (short)f2bf_bits(v);
      }
      *((short8*)&xT[t*XT_STRIDE + c0]) = pk;
    }
  }
  __syncthreads();
  const int lane = t & 63, wv = t >> 6;
  const int qd = lane >> 4, ln = lane & 15;
  short8 A[RT][2];
  #pragma unroll
  for (int rt = 0; rt < RT; ++rt) {
    #pragma unroll
    for (int kh = 0; kh < 2; ++kh) {
      const float* wp = wN + (size_t)(rt*16 + ln)*64 + kh*32 + qd*8;
      float4 f0 = *(const float4*)wp;
      float4 f1 = *(const float4*)(wp + 4);
      short8 a;
      a[0]=(short)f2bf_bits(f0.x); a[1]=(short)f2bf_bits(f0.y);
      a[2]=(short)f2bf_bits(f0.z); a[3]=(short)f2bf_bits(f0.w);
      a[4]=(short)f2bf_bits(f1.x); a[5]=(short)f2bf_bits(f1.y);
      a[6]=(short)f2bf_bits(f1.z); a[7]=(short)f2bf_bits(f1.w);
      A[rt][kh] = a;
    }
  }
  floatx4 acc[RT][4];
  #pragma unroll
  for (int rt = 0; rt < RT; ++rt)
    #pragma unroll
    for (int ct = 0; ct < 4; ++ct)
      acc[rt][ct] = (floatx4)0.f;
  #pragma unroll
  for (int ct = 0; ct < 4; ++ct) {
    const int coll = wv*64 + ct*16 + ln;
    short8 B0 = *((const short8*)&xT[coll*XT_STRIDE + qd*8]);
    short8 B1 = *((const short8*)&xT[coll*XT_STRIDE + 32 + qd*8]);
    #pragma unroll
    for (int rt = 0; rt < RT; ++rt) {
      acc[rt][ct] = __builtin_amdgcn_mfma_f32_16x16x32_bf16(A[rt][0], B0, acc[rt][ct], 0,0,0);
      acc[rt][ct] = __builtin_amdgcn_mfma_f32_16x16x32_bf16(A[rt][1], B1, acc[rt][ct], 0,0,0);
    }
  }
  // ---- epilogue: bias, store (or max), fused per-channel stats ----
  float* dst = accum + (size_t)(blockIdx.x & (NBUCK-1))*(2*CO);
  const int bs0 = (col0 + wv*64) >> 5;     // wave covers bs0, bs0+1
  #pragma unroll
  for (int rt = 0; rt < RT; ++rt) {
    float s[4]  = {0.f,0.f,0.f,0.f};
    float sq[4] = {0.f,0.f,0.f,0.f};
    float mxv[2][4];
    #pragma unroll
    for (int h = 0; h < 2; ++h)
      #pragma unroll
      for (int r = 0; r < 4; ++r) mxv[h][r] = -3.402823466e38f;
    #pragma unroll
    for (int ct = 0; ct < 4; ++ct) {
      const int col = col0 + wv*64 + ct*16 + ln;
      #pragma unroll
      for (int r = 0; r < 4; ++r) {
        const int o = rt*16 + qd*4 + r;
        float v = acc[rt][ct][r] + bias_s[o];
        if (!POOL) xout[(size_t)o*NT_COLS + col] = __float2bfloat16(v);
        else mxv[ct>>1][r] = fmaxf(mxv[ct>>1][r], v);
        s[r] += v; sq[r] = fmaf(v, v, sq[r]);
      }
    }
    if (POOL) {
      #pragma unroll
      for (int h = 0; h < 2; ++h) {
        #pragma unroll
        for (int r = 0; r < 4; ++r) {
          float m = mxv[h][r];
          m = fmax_dpp<0x111,0xF,0xF>(m);
          m = fmax_dpp<0x112,0xF,0xF>(m);
          m = fmax_dpp<0x114,0xF,0xF>(m);
          m = fmax_dpp<0x118,0xF,0xF>(m);
          if (ln == 15) {
            const int o = rt*16 + qd*4 + r;
            mx[(size_t)o*(NT_COLS/NK) + bs0 + h] = m;
          }
        }
      }
    }
    #pragma unroll
    for (int r = 0; r < 4; ++r) {
      float a = s[r], q = sq[r];
      a = add_dpp<0x111>(a); a = add_dpp<0x112>(a);
      a = add_dpp<0x114>(a); a = add_dpp<0x118>(a);
      q = add_dpp<0x111>(q); q = add_dpp<0x112>(q);
      q = add_dpp<0x114>(q); q = add_dpp<0x118>(q);
      if (ln == 15) {
        const int o = rt*16 + qd*4 + r;
        atomicAdd(&dst[o], a);
        atomicAdd(&dst[CO + o], q);
      }
    }
  }
}

// ---------------- final BN+ReLU on pooled maxes (fp32 out) ------------------
__global__ __launch_bounds__(256) void k_bnmax(const float* __restrict__ mx,
                                               const float* __restrict__ scsh,
                                               float* __restrict__ out1) {
  const int blk = blockIdx.x;        // 16 b x 128 o
  const int o = blk & 127;
  const int b = blk >> 7;
  const float sc = scsh[o], sh = scsh[128+o];
  const int s = threadIdx.x * 4;
  float4 v = *(const float4*)(mx + (size_t)o*(NT_COLS/NK) + b*NS + s);
  float4 r;
  r.x = fmaxf(fmaf(v.x, sc, sh), 0.f);
  r.y = fmaxf(fmaf(v.y, sc, sh), 0.f);
  r.z = fmaxf(fmaf(v.z, sc, sh), 0.f);
  r.w = fmaxf(fmaf(v.w, sc, sh), 0.f);
  *(float4*)(out1 + (size_t)(b*128 + o)*NS + s) = r;
}

extern "C" void kernel_launch(void* const* d_in, const int* in_sizes, int n_in,
                              void* d_out, int out_size, void* d_ws, size_t ws_size,
                              hipStream_t stream) {
  const float* xyz  = (const float*)d_in[0];
  const float* feat = (const float*)d_in[1];
  const float* w0 = (const float*)d_in[2];
  const float* b0 = (const float*)d_in[3];
  const float* g0 = (const float*)d_in[4];
  const float* bt0= (const float*)d_in[5];
  const float* w1 = (const float*)d_in[6];
  const float* b1 = (const float*)d_in[7];
  const float* g1 = (const float*)d_in[8];
  const float* bt1= (const float*)d_in[9];
  const float* w2 = (const float*)d_in[10];
  const float* b2 = (const float*)d_in[11];
  const float* g2 = (const float*)d_in[12];
  const float* bt2= (const float*)d_in[13];

  float* out0 = (float*)d_out;                     // (B,3,NS) fp32
  float* out1 = out0 + (size_t)NB*3*NS;            // (B,128,NS) fp32

  // Workspace (max offset 145,033,216 B ~= 138 MB; ws >= 194 MB proven):
  //   accum@0 (128KB), scsh@131072, newxyz@133120, bidx@329728,
  //   x2@2426880 (64MB), x1@69535744 (64MB), mx3@136644608 (8MB fp32)
  char* ws = (char*)d_ws;
  float* accum  = (float*)(ws + 0);
  float* acc_l1 = accum;                 // NBUCK x 128
  float* acc_l2 = accum + 8192;          // NBUCK x 128
  float* acc_l3 = accum + 16384;         // NBUCK x 256
  float* scsh   = (float*)(ws + 131072);
  float* newxyz = (float*)(ws + 133120);
  int*   bidx   = (int*)  (ws + 329728);
  bf16*  x2     = (bf16*) (ws + 2426880);
  bf16*  x1     = (bf16*) (ws + 69535744);
  float* mx3    = (float*)(ws + 136644608);

  k_zero <<<128, 256, 0, stream>>>(accum);

  k_fps  <<<NB,   256, 0, stream>>>(xyz, newxyz, out0);
  k_ballq<<<16384/4, 256, 0, stream>>>(xyz, newxyz, bidx);
  k_layer1<<<NT_COLS/256, 256, 0, stream>>>(xyz, feat, newxyz, bidx, w0, b0, x1);

  k_stats   <<<64*32, 256, 0, stream>>>(x1, acc_l1, 64);
  k_finalize<<<1,     256, 0, stream>>>(acc_l1, g0, bt0, scsh + 0, 64);

  k_layerN_mfma<64,false><<<NT_COLS/256, 256, 0, stream>>>(x1, w1, b1, scsh + 0, acc_l2, x2, nullptr);
  k_finalize<<<1,     256, 0, stream>>>(acc_l2, g1, bt1, scsh + 128, 64);

  k_layerN_mfma<128,true><<<NT_COLS/256, 256, 0, stream>>>(x2, w2, b2, scsh + 128, acc_l3, nullptr, mx3);
  k_finalize<<<1,     256, 0, stream>>>(acc_l3, g2, bt2, scsh + 256, 128);

  k_bnmax <<<NB*128, 256, 0, stream>>>(mx3, scsh + 256, out1);
}